// Round 15
// baseline (193.392 us; speedup 1.0000x reference)
//
#include <hip/hip_runtime.h>

#define DIMSZ 1024
#define NB 8
#define TSEQ 2048
#define MTOT (NB*TSEQ)   // 16384
#define CCH 32           // chunks per sequence
#define LCH (TSEQ/CCH)   // 64 steps per chunk
#define NCHAN (NB*DIMSZ) // 8192 independent channels

typedef __attribute__((ext_vector_type(8))) short short8v;
typedef __attribute__((ext_vector_type(4))) float f32x4;

__device__ __forceinline__ unsigned short f2bf(float f) {
  unsigned int u; __builtin_memcpy(&u, &f, 4);
  unsigned int r = u + 0x7FFF + ((u >> 16) & 1);   // RNE
  return (unsigned short)(r >> 16);
}
__device__ __forceinline__ float bf2f(unsigned short us) {
  unsigned int v = ((unsigned int)us) << 16;
  float f; __builtin_memcpy(&f, &v, 4); return f;
}

// async global->LDS, 16B per lane; LDS dest is wave-uniform base + lane*16
__device__ __forceinline__ void gload16(const void* g, void* l) {
  __builtin_amdgcn_global_load_lds(
      (const __attribute__((address_space(1))) void*)g,
      (__attribute__((address_space(3))) void*)l, 16, 0, 0);
}

// ---------------- cast x (f32) -> bf16, 4 elems/thread ----------------
__global__ __launch_bounds__(256) void cast_x_kernel(
    const float* __restrict__ in, unsigned short* __restrict__ out) {
  int i = blockIdx.x * 256 + threadIdx.x;
  float4 f = reinterpret_cast<const float4*>(in)[i];
  uint2 o;
  o.x = (unsigned)f2bf(f.x) | ((unsigned)f2bf(f.y) << 16);
  o.y = (unsigned)f2bf(f.z) | ((unsigned)f2bf(f.w) << 16);
  reinterpret_cast<uint2*>(out)[i] = o;
}

// ------- transpose + cast, 3 weight matrices in ONE launch (z selects) -------
__global__ __launch_bounds__(256) void transpose_cast3_kernel(
    const float* __restrict__ Wk, const float* __restrict__ Wv,
    const float* __restrict__ Wo,
    unsigned short* __restrict__ WTk, unsigned short* __restrict__ WTv,
    unsigned short* __restrict__ WTo) {
  const float* W = (blockIdx.z == 0) ? Wk : (blockIdx.z == 1) ? Wv : Wo;
  unsigned short* WT = (blockIdx.z == 0) ? WTk : (blockIdx.z == 1) ? WTv : WTo;
  __shared__ float tile[32][33];
  int tx = threadIdx.x & 31, ty = threadIdx.x >> 5;   // 32 x 8
  int row0 = blockIdx.y * 32, col0 = blockIdx.x * 32;
  #pragma unroll
  for (int j = 0; j < 32; j += 8)
    tile[ty + j][tx] = W[(size_t)(row0 + ty + j) * DIMSZ + col0 + tx];
  __syncthreads();
  #pragma unroll
  for (int j = 0; j < 32; j += 8)
    WT[(size_t)(col0 + ty + j) * DIMSZ + row0 + tx] = f2bf(tile[tx][ty + j]);
}

// =============== 256x256 8-phase bf16 MFMA GEMM (R6 schedule — best) ===============
// 512 thr = 8 waves (2M x 4N), per-wave C 128x64 (8x4 16x16 frags), BK=64.
// LDS: 2 K-tile buffers x (A 256x64 + B 256x64) bf16 = 128 KiB (dynamic).
// Effective layout byte(row,cb)=row*128+(cb^((row&7)<<4)) via pre-swizzled
// global source (linear gload_lds dest) + same XOR on ds_read (conflicts=0).
// Fragments read ONCE per K-tile and held (a0,b0@ph0, b1@ph1, a1@ph2; ph3
// none) = 24 ds_read_b128/wave/K-tile. Stage order A0,B0,B1,A1; counted
// vmcnt(4)@ph0,1,3; tail drains 2->0. Benched best of 9 variants (x3 runs):
// 75.5us, 919 TF — the documented ~900 TF plateau for compiler-scheduled
// HIP gload_lds pipelines (only HK-exact/hand-asm exceeds it).

#define VM4 asm volatile("s_waitcnt vmcnt(4)" ::: "memory")
#define VM2 asm volatile("s_waitcnt vmcnt(2)" ::: "memory")
#define VM0 asm volatile("s_waitcnt vmcnt(0)" ::: "memory")

#define PH_BAR do {                         \
  __builtin_amdgcn_s_barrier();             \
  __builtin_amdgcn_sched_barrier(0);        \
} while(0)

// stage one 128-row half-tile of operand OP (0=A,1=B), half HALF, K-tile T
// into buffer BUF. Each wave: 2 gload (rows wid*16..+15 of the half).
#define STAGE(BUF, OP, HALF, T) do {                                        \
  const unsigned short* _s = (OP) ? BT : Aop;                               \
  const int _rb = ((OP) ? bcol : brow) + (HALF)*128 + wid*16;               \
  char* _lb = smem + (BUF)*65536 + (OP)*32768 + ((HALF)*128 + wid*16)*128;  \
  const size_t _k0 = (size_t)(T)*64;                                        \
  gload16(&_s[(size_t)(_rb + srow)*K + _k0 + (sg^srow)*8], _lb);            \
  gload16(&_s[(size_t)(_rb + 8 + srow)*K + _k0 + (sg^srow)*8], _lb + 1024); \
} while(0)

#define READ_A(DST, BUF, MH) do {                                           \
  _Pragma("unroll")                                                         \
  for (int _m = 0; _m < 4; ++_m) {                                          \
    const char* _pa = smem + (BUF)*65536 +                                  \
        ((MH)*128 + wr*64 + _m*16 + lrow)*128;                              \
    DST[_m][0] = *(const short8v*)(_pa + ((lko*2) ^ rds));                  \
    DST[_m][1] = *(const short8v*)(_pa + (((32+lko)*2) ^ rds));             \
  }                                                                         \
} while(0)

#define READ_B(DST, BUF, NH) do {                                           \
  _Pragma("unroll")                                                         \
  for (int _n = 0; _n < 2; ++_n) {                                          \
    const char* _pb = smem + (BUF)*65536 + 32768 +                          \
        ((NH)*128 + wc*32 + _n*16 + lrow)*128;                              \
    DST[_n][0] = *(const short8v*)(_pb + ((lko*2) ^ rds));                  \
    DST[_n][1] = *(const short8v*)(_pb + (((32+lko)*2) ^ rds));             \
  }                                                                         \
} while(0)

#define MFMA_Q(MH, NH, AF, BF) do {                                         \
  __builtin_amdgcn_s_setprio(1);                                            \
  _Pragma("unroll")                                                         \
  for (int _m = 0; _m < 4; ++_m)                                            \
    _Pragma("unroll")                                                       \
    for (int _n = 0; _n < 2; ++_n) {                                        \
      acc[(MH)*4+_m][(NH)*2+_n] = __builtin_amdgcn_mfma_f32_16x16x32_bf16(  \
          AF[_m][0], BF[_n][0], acc[(MH)*4+_m][(NH)*2+_n], 0, 0, 0);        \
      acc[(MH)*4+_m][(NH)*2+_n] = __builtin_amdgcn_mfma_f32_16x16x32_bf16(  \
          AF[_m][1], BF[_n][1], acc[(MH)*4+_m][(NH)*2+_n], 0, 0, 0);        \
    }                                                                       \
  __builtin_amdgcn_s_setprio(0);                                            \
  PH_BAR;                                                                   \
} while(0)

template<int OUTBF>
__global__ __launch_bounds__(512) void gemm256_kernel(
    const unsigned short* __restrict__ Aop,
    const unsigned short* __restrict__ BT,
    void* __restrict__ Cv,
    const float* __restrict__ bias0,
    const float* __restrict__ bias1,
    int M, int N, int K, int Nsplit) {
  extern __shared__ char smem[];
  const int tid  = threadIdx.x;
  const int wid  = tid >> 6;          // 0..7
  const int lane = tid & 63;
  const int wr   = wid >> 2;          // 0..1  (M-warps)
  const int wc   = wid & 3;           // 0..3  (N-warps)
  const int brow = blockIdx.x * 256;
  const int bcol = blockIdx.y * 256;
  const int lrow = lane & 15;
  const int lko  = (lane >> 4) * 8;   // elems
  const int rds  = (lrow & 7) << 4;   // read-side XOR (bytes)
  const int srow = lane >> 3;         // staging row in 8-row group
  const int sg   = lane & 7;          // staging granule

  f32x4 acc[8][4];
  #pragma unroll
  for (int m = 0; m < 8; ++m)
    #pragma unroll
    for (int n = 0; n < 4; ++n)
      acc[m][n] = (f32x4){0.f, 0.f, 0.f, 0.f};

  short8v a0[4][2], a1[4][2], bf0[2][2], bf1[2][2];

  // prologue: stage tile 0 (A0,B0,B1,A1), publish A0+B0 (VM4 leaves B1,A1)
  STAGE(0, 0, 0, 0);
  STAGE(0, 1, 0, 0);
  STAGE(0, 1, 1, 0);
  STAGE(0, 0, 1, 0);
  VM4;
  PH_BAR;

  const int NT = K >> 6;
  for (int t = 0; t < NT - 1; ++t) {
    const int b = t & 1, nb = b ^ 1;
    // ph0: read a0,b0; stage (t+1).A0; VM4 publishes B1(t)
    READ_A(a0, b, 0); READ_B(bf0, b, 0);
    STAGE(nb, 0, 0, t + 1); VM4; PH_BAR;
    MFMA_Q(0, 0, a0, bf0);
    // ph1: read b1; stage (t+1).B0; VM4 publishes A1(t)
    READ_B(bf1, b, 1);
    STAGE(nb, 1, 0, t + 1); VM4; PH_BAR;
    MFMA_Q(0, 1, a0, bf1);
    // ph2: read a1; stage (t+1).B1
    READ_A(a1, b, 1);
    STAGE(nb, 1, 1, t + 1); PH_BAR;
    MFMA_Q(1, 0, a1, bf0);
    // ph3: no reads; stage (t+1).A1; VM4 publishes A0(t+1),B0(t+1)
    STAGE(nb, 0, 1, t + 1); VM4; PH_BAR;
    MFMA_Q(1, 1, a1, bf1);
  }
  {
    const int b = (NT - 1) & 1;
    READ_A(a0, b, 0); READ_B(bf0, b, 0);
    VM2; PH_BAR;              // publish B1(NT-1)
    MFMA_Q(0, 0, a0, bf0);
    READ_B(bf1, b, 1);
    VM0; PH_BAR;              // publish A1(NT-1)
    MFMA_Q(0, 1, a0, bf1);
    READ_A(a1, b, 1);
    PH_BAR;
    MFMA_Q(1, 0, a1, bf0);
    PH_BAR;
    MFMA_Q(1, 1, a1, bf1);
  }

  // epilogue: C write (+bias)
  #pragma unroll
  for (int mf = 0; mf < 8; ++mf) {
    const int rowb = brow + (mf >= 4) * 128 + wr * 64 + (mf & 3) * 16 + (lane >> 4) * 4;
    #pragma unroll
    for (int nf = 0; nf < 4; ++nf) {
      const int col = bcol + (nf >= 2) * 128 + wc * 32 + (nf & 1) * 16 + lrow;
      const float bb = (col < Nsplit) ? bias0[col] : bias1[col - Nsplit];
      #pragma unroll
      for (int r = 0; r < 4; ++r) {
        const float val = acc[mf][nf][r] + bb;
        if (OUTBF) {
          ((unsigned short*)Cv)[(size_t)(rowb + r) * N + col] = f2bf(val);
        } else {
          ((float*)Cv)[(size_t)(rowb + r) * N + col] = val;
        }
      }
    }
  }
}

// =================== WKV chunked parallel scan ===================
// State (p,a,b): A = a*e^p, B = b*e^p. Empty state (p=-1e30,a=b=0) reproduces
// the reference init and O[0]=v[0] through the uniform step rule.

__device__ __forceinline__ void wkv_step(float& p, float& a, float& b,
                                         float kt, float vt, float w) {
  float ww2 = p - w;
  float qq2 = fmaxf(ww2, kt);
  float e1 = __expf(ww2 - qq2);
  float e2 = __expf(kt - qq2);
  a = e1 * a + e2 * vt;
  b = e1 * b + e2;
  p = qq2;
}

// Pass 1: per-(chunk, channel-octet) local state from empty. 8 channels/thread
// (16B uint4 kv loads — G13 sweet spot).
__global__ __launch_bounds__(256) void wkv_chunk_state_kernel(
    const unsigned short* __restrict__ kv,
    const float* __restrict__ wdec,
    float* __restrict__ stP, float* __restrict__ stA, float* __restrict__ stB) {
  int idx = blockIdx.x * 256 + threadIdx.x;     // 0 .. CCH*NB*128-1
  int co = idx & 127;
  int n = (idx >> 7) & (NB - 1);
  int chunk = idx >> 10;
  int c = co * 8;
  float w8[8];
  *reinterpret_cast<float4*>(&w8[0]) = *reinterpret_cast<const float4*>(&wdec[c]);
  *reinterpret_cast<float4*>(&w8[4]) = *reinterpret_cast<const float4*>(&wdec[c + 4]);
  const unsigned short* base = kv + (size_t)(n * TSEQ + chunk * LCH) * 2048 + c;
  float p[8], a[8], b[8];
  #pragma unroll
  for (int q = 0; q < 8; ++q) { p[q] = -1e30f; a[q] = 0.f; b[q] = 0.f; }
  #pragma unroll 4
  for (int j = 0; j < LCH; ++j) {
    uint4 kk = *reinterpret_cast<const uint4*>(&base[(size_t)j * 2048]);
    uint4 vv = *reinterpret_cast<const uint4*>(&base[(size_t)j * 2048 + 1024]);
    const unsigned kw[4] = {kk.x, kk.y, kk.z, kk.w};
    const unsigned vw[4] = {vv.x, vv.y, vv.z, vv.w};
    #pragma unroll
    for (int q = 0; q < 4; ++q) {
      wkv_step(p[2*q],   a[2*q],   b[2*q],   bf2f(kw[q] & 0xffff), bf2f(vw[q] & 0xffff), w8[2*q]);
      wkv_step(p[2*q+1], a[2*q+1], b[2*q+1], bf2f(kw[q] >> 16),    bf2f(vw[q] >> 16),    w8[2*q+1]);
    }
  }
  int soff = chunk * NCHAN + n * 1024 + c;
  #pragma unroll
  for (int h = 0; h < 2; ++h) {
    *reinterpret_cast<float4*>(&stP[soff + 4*h]) = *reinterpret_cast<float4*>(&p[4*h]);
    *reinterpret_cast<float4*>(&stA[soff + 4*h]) = *reinterpret_cast<float4*>(&a[4*h]);
    *reinterpret_cast<float4*>(&stB[soff + 4*h]) = *reinterpret_cast<float4*>(&b[4*h]);
  }
}

// Pass 2: serial scan over chunk states per channel -> incoming prefixes.
__global__ __launch_bounds__(256) void wkv_scan_kernel(
    const float* __restrict__ wdec,
    float* __restrict__ stP, float* __restrict__ stA, float* __restrict__ stB) {
  int idx = blockIdx.x * 256 + threadIdx.x;   // [n][c]
  int c = idx & 1023;
  float decay = (float)LCH * wdec[c];
  float p = -1e30f, a = 0.f, b = 0.f;
  for (int i = 0; i < CCH; ++i) {
    int off = i * NCHAN + idx;
    float pc = stP[off], ac = stA[off], bc = stB[off];
    stP[off] = p; stA[off] = a; stB[off] = b;   // incoming prefix
    float pd = p - decay;
    float q = fmaxf(pd, pc);
    float e1 = __expf(pd - q);
    float e2 = __expf(pc - q);
    a = e1 * a + e2 * ac;
    b = e1 * b + e2 * bc;
    p = q;
  }
}

// Pass 3: replay each chunk from its incoming prefix, emitting outputs.
// 8 channels/thread (16B loads + 16B stores).
__global__ __launch_bounds__(256) void wkv_out_kernel(
    const unsigned short* __restrict__ kv,
    const float* __restrict__ wdec, const float* __restrict__ ubon,
    const float* __restrict__ stP, const float* __restrict__ stA,
    const float* __restrict__ stB,
    unsigned short* __restrict__ O) {
  int idx = blockIdx.x * 256 + threadIdx.x;
  int co = idx & 127;
  int n = (idx >> 7) & (NB - 1);
  int chunk = idx >> 10;
  int c = co * 8;
  float w8[8], u8[8];
  *reinterpret_cast<float4*>(&w8[0]) = *reinterpret_cast<const float4*>(&wdec[c]);
  *reinterpret_cast<float4*>(&w8[4]) = *reinterpret_cast<const float4*>(&wdec[c + 4]);
  *reinterpret_cast<float4*>(&u8[0]) = *reinterpret_cast<const float4*>(&ubon[c]);
  *reinterpret_cast<float4*>(&u8[4]) = *reinterpret_cast<const float4*>(&ubon[c + 4]);
  const unsigned short* base = kv + (size_t)(n * TSEQ + chunk * LCH) * 2048 + c;
  unsigned short* ob = O + (size_t)(n * TSEQ + chunk * LCH) * DIMSZ + c;
  int soff = chunk * NCHAN + n * 1024 + c;
  float p[8], a[8], b[8];
  #pragma unroll
  for (int h = 0; h < 2; ++h) {
    *reinterpret_cast<float4*>(&p[4*h]) = *reinterpret_cast<const float4*>(&stP[soff + 4*h]);
    *reinterpret_cast<float4*>(&a[4*h]) = *reinterpret_cast<const float4*>(&stA[soff + 4*h]);
    *reinterpret_cast<float4*>(&b[4*h]) = *reinterpret_cast<const float4*>(&stB[soff + 4*h]);
  }
  #pragma unroll 2
  for (int j = 0; j < LCH; ++j) {
    uint4 kk = *reinterpret_cast<const uint4*>(&base[(size_t)j * 2048]);
    uint4 vv = *reinterpret_cast<const uint4*>(&base[(size_t)j * 2048 + 1024]);
    const unsigned kw[4] = {kk.x, kk.y, kk.z, kk.w};
    const unsigned vw[4] = {vv.x, vv.y, vv.z, vv.w};
    unsigned ow[4];
    #pragma unroll
    for (int q = 0; q < 4; ++q) {
      float k0 = bf2f(kw[q] & 0xffff), k1 = bf2f(kw[q] >> 16);
      float v0 = bf2f(vw[q] & 0xffff), v1 = bf2f(vw[q] >> 16);
      int c0 = 2*q, c1 = 2*q + 1;
      // outputs from incoming state (bonus u)
      float ww0 = u8[c0] + k0, ww1 = u8[c1] + k1;
      float qq0 = fmaxf(ww0, p[c0]), qq1 = fmaxf(ww1, p[c1]);
      float e10 = __expf(p[c0] - qq0), e20 = __expf(ww0 - qq0);
      float e11 = __expf(p[c1] - qq1), e21 = __expf(ww1 - qq1);
      float o0 = (e10 * a[c0] + e20 * v0) * __builtin_amdgcn_rcpf(e10 * b[c0] + e20);
      float o1 = (e11 * a[c1] + e21 * v1) * __builtin_amdgcn_rcpf(e11 * b[c1] + e21);
      ow[q] = (unsigned)f2bf(o0) | ((unsigned)f2bf(o1) << 16);
      // state update (decay w)
      wkv_step(p[c0], a[c0], b[c0], k0, v0, w8[c0]);
      wkv_step(p[c1], a[c1], b[c1], k1, v1, w8[c1]);
    }
    uint4 ov = make_uint4(ow[0], ow[1], ow[2], ow[3]);
    *reinterpret_cast<uint4*>(&ob[(size_t)j * DIMSZ]) = ov;
  }
}

extern "C" void kernel_launch(void* const* d_in, const int* in_sizes, int n_in,
                              void* d_out, int out_size, void* d_ws, size_t ws_size,
                              hipStream_t stream) {
  const float* x  = (const float*)d_in[0];
  // d_in[1]=Wq, d_in[2]=bq: unused by the reference forward
  const float* Wk = (const float*)d_in[3];
  const float* bk = (const float*)d_in[4];
  const float* Wv = (const float*)d_in[5];
  const float* bv = (const float*)d_in[6];
  const float* wr = (const float*)d_in[7];
  const float* ur = (const float*)d_in[8];
  const float* Wo = (const float*)d_in[9];
  const float* bo = (const float*)d_in[10];
  float* out = (float*)d_out;

  char* ws = (char*)d_ws;
  unsigned short* xb   = (unsigned short*)(ws);               // 32MB  [16384][1024] bf16 (reused as O)
  unsigned short* WTkv = (unsigned short*)(ws + 33554432);    // 4MB   [2048][1024] bf16 (Wk^T ; Wv^T)
  unsigned short* WoT  = (unsigned short*)(ws + 37748736);    // 2MB   [1024][1024] bf16
  unsigned short* kvb  = (unsigned short*)(ws + 39845888);    // 64MB  [16384][2048] bf16

  // chunk-state scratch lives in d_out (64MB f32): fully overwritten by the
  // final GEMM afterwards, so this is free scratch during the wkv phase.
  float* stP = out;                       // 1MB (CCH*NCHAN floats)
  float* stA = out + CCH * NCHAN;         // 1MB
  float* stB = out + 2 * CCH * NCHAN;     // 1MB

  cast_x_kernel<<<dim3(16384), dim3(256), 0, stream>>>(x, xb);
  transpose_cast3_kernel<<<dim3(32, 32, 3), dim3(256), 0, stream>>>(
      Wk, Wv, Wo, WTkv, WTkv + 1024 * 1024, WoT);

  // k|v projection: [16384][1024] @ [1024][2048] -> bf16 kv buffer (+bk|bv)
  gemm256_kernel<1><<<dim3(64, 8), dim3(512), 131072, stream>>>(
      xb, WTkv, (void*)kvb, bk, bv, MTOT, 2048, 1024, 1024);

  // WKV chunked scan -> O (bf16) into xb (its x-bf16 contents are consumed)
  wkv_chunk_state_kernel<<<dim3(CCH * NB * 128 / 256), dim3(256), 0, stream>>>(
      kvb, wr, stP, stA, stB);
  wkv_scan_kernel<<<dim3(NCHAN / 256), dim3(256), 0, stream>>>(wr, stP, stA, stB);
  wkv_out_kernel<<<dim3(CCH * NB * 128 / 256), dim3(256), 0, stream>>>(
      kvb, wr, ur, stP, stA, stB, xb);

  // output projection: [16384][1024] @ [1024][1024] -> f32 d_out (+bo)
  gemm256_kernel<0><<<dim3(64, 4), dim3(512), 131072, stream>>>(
      xb, WoT, (void*)out, bo, bo, MTOT, 1024, 1024, 1024);
}

// Round 16
// 167.460 us; speedup vs baseline: 1.1549x; 1.1549x over previous
//
#include <hip/hip_runtime.h>

#define DIMSZ 1024
#define NB 8
#define TSEQ 2048
#define MTOT (NB*TSEQ)   // 16384
#define CCH 64           // chunks per sequence
#define LCH (TSEQ/CCH)   // 32 steps per chunk
#define NCHAN (NB*DIMSZ) // 8192 independent channels

typedef __attribute__((ext_vector_type(8))) short short8v;
typedef __attribute__((ext_vector_type(4))) float f32x4;

__device__ __forceinline__ unsigned short f2bf(float f) {
  unsigned int u; __builtin_memcpy(&u, &f, 4);
  unsigned int r = u + 0x7FFF + ((u >> 16) & 1);   // RNE
  return (unsigned short)(r >> 16);
}
__device__ __forceinline__ float bf2f(unsigned short us) {
  unsigned int v = ((unsigned int)us) << 16;
  float f; __builtin_memcpy(&f, &v, 4); return f;
}

// async global->LDS, 16B per lane; LDS dest is wave-uniform base + lane*16
__device__ __forceinline__ void gload16(const void* g, void* l) {
  __builtin_amdgcn_global_load_lds(
      (const __attribute__((address_space(1))) void*)g,
      (__attribute__((address_space(3))) void*)l, 16, 0, 0);
}

// ---------------- cast x (f32) -> bf16, 4 elems/thread ----------------
__global__ __launch_bounds__(256) void cast_x_kernel(
    const float* __restrict__ in, unsigned short* __restrict__ out) {
  int i = blockIdx.x * 256 + threadIdx.x;
  float4 f = reinterpret_cast<const float4*>(in)[i];
  uint2 o;
  o.x = (unsigned)f2bf(f.x) | ((unsigned)f2bf(f.y) << 16);
  o.y = (unsigned)f2bf(f.z) | ((unsigned)f2bf(f.w) << 16);
  reinterpret_cast<uint2*>(out)[i] = o;
}

// ------- transpose + cast, 3 weight matrices in ONE launch (z selects) -------
__global__ __launch_bounds__(256) void transpose_cast3_kernel(
    const float* __restrict__ Wk, const float* __restrict__ Wv,
    const float* __restrict__ Wo,
    unsigned short* __restrict__ WTk, unsigned short* __restrict__ WTv,
    unsigned short* __restrict__ WTo) {
  const float* W = (blockIdx.z == 0) ? Wk : (blockIdx.z == 1) ? Wv : Wo;
  unsigned short* WT = (blockIdx.z == 0) ? WTk : (blockIdx.z == 1) ? WTv : WTo;
  __shared__ float tile[32][33];
  int tx = threadIdx.x & 31, ty = threadIdx.x >> 5;   // 32 x 8
  int row0 = blockIdx.y * 32, col0 = blockIdx.x * 32;
  #pragma unroll
  for (int j = 0; j < 32; j += 8)
    tile[ty + j][tx] = W[(size_t)(row0 + ty + j) * DIMSZ + col0 + tx];
  __syncthreads();
  #pragma unroll
  for (int j = 0; j < 32; j += 8)
    WT[(size_t)(col0 + ty + j) * DIMSZ + row0 + tx] = f2bf(tile[tx][ty + j]);
}

// =============== 256x256 8-phase bf16 MFMA GEMM (R6 schedule — best) ===============
// 512 thr = 8 waves (2M x 4N), per-wave C 128x64 (8x4 16x16 frags), BK=64.
// LDS: 2 K-tile buffers x (A 256x64 + B 256x64) bf16 = 128 KiB (dynamic).
// Effective layout byte(row,cb)=row*128+(cb^((row&7)<<4)) via pre-swizzled
// global source (linear gload_lds dest) + same XOR on ds_read (conflicts=0).
// Fragments read ONCE per K-tile and held (a0,b0@ph0, b1@ph1, a1@ph2; ph3
// none) = 24 ds_read_b128/wave/K-tile. Stage order A0,B0,B1,A1; counted
// vmcnt(4)@ph0,1,3; tail drains 2->0. Benched best of 9 variants (x3 runs):
// 75.5us, 919 TF — the documented ~900 TF plateau for compiler-scheduled
// HIP gload_lds pipelines (only HK-exact/hand-asm exceeds it).

#define VM4 asm volatile("s_waitcnt vmcnt(4)" ::: "memory")
#define VM2 asm volatile("s_waitcnt vmcnt(2)" ::: "memory")
#define VM0 asm volatile("s_waitcnt vmcnt(0)" ::: "memory")

#define PH_BAR do {                         \
  __builtin_amdgcn_s_barrier();             \
  __builtin_amdgcn_sched_barrier(0);        \
} while(0)

// stage one 128-row half-tile of operand OP (0=A,1=B), half HALF, K-tile T
// into buffer BUF. Each wave: 2 gload (rows wid*16..+15 of the half).
#define STAGE(BUF, OP, HALF, T) do {                                        \
  const unsigned short* _s = (OP) ? BT : Aop;                               \
  const int _rb = ((OP) ? bcol : brow) + (HALF)*128 + wid*16;               \
  char* _lb = smem + (BUF)*65536 + (OP)*32768 + ((HALF)*128 + wid*16)*128;  \
  const size_t _k0 = (size_t)(T)*64;                                        \
  gload16(&_s[(size_t)(_rb + srow)*K + _k0 + (sg^srow)*8], _lb);            \
  gload16(&_s[(size_t)(_rb + 8 + srow)*K + _k0 + (sg^srow)*8], _lb + 1024); \
} while(0)

#define READ_A(DST, BUF, MH) do {                                           \
  _Pragma("unroll")                                                         \
  for (int _m = 0; _m < 4; ++_m) {                                          \
    const char* _pa = smem + (BUF)*65536 +                                  \
        ((MH)*128 + wr*64 + _m*16 + lrow)*128;                              \
    DST[_m][0] = *(const short8v*)(_pa + ((lko*2) ^ rds));                  \
    DST[_m][1] = *(const short8v*)(_pa + (((32+lko)*2) ^ rds));             \
  }                                                                         \
} while(0)

#define READ_B(DST, BUF, NH) do {                                           \
  _Pragma("unroll")                                                         \
  for (int _n = 0; _n < 2; ++_n) {                                          \
    const char* _pb = smem + (BUF)*65536 + 32768 +                          \
        ((NH)*128 + wc*32 + _n*16 + lrow)*128;                              \
    DST[_n][0] = *(const short8v*)(_pb + ((lko*2) ^ rds));                  \
    DST[_n][1] = *(const short8v*)(_pb + (((32+lko)*2) ^ rds));             \
  }                                                                         \
} while(0)

#define MFMA_Q(MH, NH, AF, BF) do {                                         \
  __builtin_amdgcn_s_setprio(1);                                            \
  _Pragma("unroll")                                                         \
  for (int _m = 0; _m < 4; ++_m)                                            \
    _Pragma("unroll")                                                       \
    for (int _n = 0; _n < 2; ++_n) {                                        \
      acc[(MH)*4+_m][(NH)*2+_n] = __builtin_amdgcn_mfma_f32_16x16x32_bf16(  \
          AF[_m][0], BF[_n][0], acc[(MH)*4+_m][(NH)*2+_n], 0, 0, 0);        \
      acc[(MH)*4+_m][(NH)*2+_n] = __builtin_amdgcn_mfma_f32_16x16x32_bf16(  \
          AF[_m][1], BF[_n][1], acc[(MH)*4+_m][(NH)*2+_n], 0, 0, 0);        \
    }                                                                       \
  __builtin_amdgcn_s_setprio(0);                                            \
  PH_BAR;                                                                   \
} while(0)

template<int OUTBF>
__global__ __launch_bounds__(512) void gemm256_kernel(
    const unsigned short* __restrict__ Aop,
    const unsigned short* __restrict__ BT,
    void* __restrict__ Cv,
    const float* __restrict__ bias0,
    const float* __restrict__ bias1,
    int M, int N, int K, int Nsplit) {
  extern __shared__ char smem[];
  const int tid  = threadIdx.x;
  const int wid  = tid >> 6;          // 0..7
  const int lane = tid & 63;
  const int wr   = wid >> 2;          // 0..1  (M-warps)
  const int wc   = wid & 3;           // 0..3  (N-warps)
  const int brow = blockIdx.x * 256;
  const int bcol = blockIdx.y * 256;
  const int lrow = lane & 15;
  const int lko  = (lane >> 4) * 8;   // elems
  const int rds  = (lrow & 7) << 4;   // read-side XOR (bytes)
  const int srow = lane >> 3;         // staging row in 8-row group
  const int sg   = lane & 7;          // staging granule

  f32x4 acc[8][4];
  #pragma unroll
  for (int m = 0; m < 8; ++m)
    #pragma unroll
    for (int n = 0; n < 4; ++n)
      acc[m][n] = (f32x4){0.f, 0.f, 0.f, 0.f};

  short8v a0[4][2], a1[4][2], bf0[2][2], bf1[2][2];

  // prologue: stage tile 0 (A0,B0,B1,A1), publish A0+B0 (VM4 leaves B1,A1)
  STAGE(0, 0, 0, 0);
  STAGE(0, 1, 0, 0);
  STAGE(0, 1, 1, 0);
  STAGE(0, 0, 1, 0);
  VM4;
  PH_BAR;

  const int NT = K >> 6;
  for (int t = 0; t < NT - 1; ++t) {
    const int b = t & 1, nb = b ^ 1;
    // ph0: read a0,b0; stage (t+1).A0; VM4 publishes B1(t)
    READ_A(a0, b, 0); READ_B(bf0, b, 0);
    STAGE(nb, 0, 0, t + 1); VM4; PH_BAR;
    MFMA_Q(0, 0, a0, bf0);
    // ph1: read b1; stage (t+1).B0; VM4 publishes A1(t)
    READ_B(bf1, b, 1);
    STAGE(nb, 1, 0, t + 1); VM4; PH_BAR;
    MFMA_Q(0, 1, a0, bf1);
    // ph2: read a1; stage (t+1).B1
    READ_A(a1, b, 1);
    STAGE(nb, 1, 1, t + 1); PH_BAR;
    MFMA_Q(1, 0, a1, bf0);
    // ph3: no reads; stage (t+1).A1; VM4 publishes A0(t+1),B0(t+1)
    STAGE(nb, 0, 1, t + 1); VM4; PH_BAR;
    MFMA_Q(1, 1, a1, bf1);
  }
  {
    const int b = (NT - 1) & 1;
    READ_A(a0, b, 0); READ_B(bf0, b, 0);
    VM2; PH_BAR;              // publish B1(NT-1)
    MFMA_Q(0, 0, a0, bf0);
    READ_B(bf1, b, 1);
    VM0; PH_BAR;              // publish A1(NT-1)
    MFMA_Q(0, 1, a0, bf1);
    READ_A(a1, b, 1);
    PH_BAR;
    MFMA_Q(1, 0, a1, bf0);
    PH_BAR;
    MFMA_Q(1, 1, a1, bf1);
  }

  // epilogue: C write (+bias)
  #pragma unroll
  for (int mf = 0; mf < 8; ++mf) {
    const int rowb = brow + (mf >= 4) * 128 + wr * 64 + (mf & 3) * 16 + (lane >> 4) * 4;
    #pragma unroll
    for (int nf = 0; nf < 4; ++nf) {
      const int col = bcol + (nf >= 2) * 128 + wc * 32 + (nf & 1) * 16 + lrow;
      const float bb = (col < Nsplit) ? bias0[col] : bias1[col - Nsplit];
      #pragma unroll
      for (int r = 0; r < 4; ++r) {
        const float val = acc[mf][nf][r] + bb;
        if (OUTBF) {
          ((unsigned short*)Cv)[(size_t)(rowb + r) * N + col] = f2bf(val);
        } else {
          ((float*)Cv)[(size_t)(rowb + r) * N + col] = val;
        }
      }
    }
  }
}

// =================== WKV chunked parallel scan ===================
// State (p,a,b): A = a*e^p, B = b*e^p. Empty state (p=-1e30,a=b=0) reproduces
// the reference init and O[0]=v[0] through the uniform step rule.
// Occupancy note (R15 lesson): p1/p3 need >=2048 waves (2/SIMD) to hide the
// exp-chain latency; 8ch/thread+CCH=32 (512 waves) cost +26us. Keep 4ch/CCH=64.

__device__ __forceinline__ void wkv_step(float& p, float& a, float& b,
                                         float kt, float vt, float w) {
  float ww2 = p - w;
  float qq2 = fmaxf(ww2, kt);
  float e1 = __expf(ww2 - qq2);
  float e2 = __expf(kt - qq2);
  a = e1 * a + e2 * vt;
  b = e1 * b + e2;
  p = qq2;
}

// Pass 1: per-(chunk, channel-quad) local state from empty. 4 channels/thread.
__global__ __launch_bounds__(256) void wkv_chunk_state_kernel(
    const unsigned short* __restrict__ kv,
    const float* __restrict__ wdec,
    float* __restrict__ stP, float* __restrict__ stA, float* __restrict__ stB) {
  int idx = blockIdx.x * 256 + threadIdx.x;     // 0 .. CCH*NB*256-1
  int cq = idx & 255;
  int n = (idx >> 8) & (NB - 1);
  int chunk = idx >> 11;
  int c = cq * 4;
  float4 w4 = *reinterpret_cast<const float4*>(&wdec[c]);
  const unsigned short* base = kv + (size_t)(n * TSEQ + chunk * LCH) * 2048 + c;
  float p0=-1e30f,a0=0.f,b0=0.f, p1=-1e30f,a1=0.f,b1=0.f;
  float p2=-1e30f,a2=0.f,b2=0.f, p3=-1e30f,a3=0.f,b3=0.f;
  #pragma unroll 8
  for (int j = 0; j < LCH; ++j) {
    uint2 kk = *reinterpret_cast<const uint2*>(&base[(size_t)j * 2048]);
    uint2 vv = *reinterpret_cast<const uint2*>(&base[(size_t)j * 2048 + 1024]);
    wkv_step(p0,a0,b0, bf2f(kk.x & 0xffff), bf2f(vv.x & 0xffff), w4.x);
    wkv_step(p1,a1,b1, bf2f(kk.x >> 16),    bf2f(vv.x >> 16),    w4.y);
    wkv_step(p2,a2,b2, bf2f(kk.y & 0xffff), bf2f(vv.y & 0xffff), w4.z);
    wkv_step(p3,a3,b3, bf2f(kk.y >> 16),    bf2f(vv.y >> 16),    w4.w);
  }
  int soff = chunk * NCHAN + n * 1024 + c;
  *reinterpret_cast<float4*>(&stP[soff]) = make_float4(p0, p1, p2, p3);
  *reinterpret_cast<float4*>(&stA[soff]) = make_float4(a0, a1, a2, a3);
  *reinterpret_cast<float4*>(&stB[soff]) = make_float4(b0, b1, b2, b3);
}

// Pass 2: serial scan over chunk states per channel -> incoming prefixes.
__global__ __launch_bounds__(256) void wkv_scan_kernel(
    const float* __restrict__ wdec,
    float* __restrict__ stP, float* __restrict__ stA, float* __restrict__ stB) {
  int idx = blockIdx.x * 256 + threadIdx.x;   // [n][c]
  int c = idx & 1023;
  float decay = (float)LCH * wdec[c];
  float p = -1e30f, a = 0.f, b = 0.f;
  for (int i = 0; i < CCH; ++i) {
    int off = i * NCHAN + idx;
    float pc = stP[off], ac = stA[off], bc = stB[off];
    stP[off] = p; stA[off] = a; stB[off] = b;   // incoming prefix
    float pd = p - decay;
    float q = fmaxf(pd, pc);
    float e1 = __expf(pd - q);
    float e2 = __expf(pc - q);
    a = e1 * a + e2 * ac;
    b = e1 * b + e2 * bc;
    p = q;
  }
}

// Pass 3: replay each chunk from its incoming prefix, emitting outputs. 4 ch/thread.
__global__ __launch_bounds__(256) void wkv_out_kernel(
    const unsigned short* __restrict__ kv,
    const float* __restrict__ wdec, const float* __restrict__ ubon,
    const float* __restrict__ stP, const float* __restrict__ stA,
    const float* __restrict__ stB,
    unsigned short* __restrict__ O) {
  int idx = blockIdx.x * 256 + threadIdx.x;
  int cq = idx & 255;
  int n = (idx >> 8) & (NB - 1);
  int chunk = idx >> 11;
  int c = cq * 4;
  float4 w4 = *reinterpret_cast<const float4*>(&wdec[c]);
  float4 u4 = *reinterpret_cast<const float4*>(&ubon[c]);
  const unsigned short* base = kv + (size_t)(n * TSEQ + chunk * LCH) * 2048 + c;
  unsigned short* ob = O + (size_t)(n * TSEQ + chunk * LCH) * DIMSZ + c;
  int soff = chunk * NCHAN + n * 1024 + c;
  float4 pP = *reinterpret_cast<const float4*>(&stP[soff]);
  float4 pA = *reinterpret_cast<const float4*>(&stA[soff]);
  float4 pB = *reinterpret_cast<const float4*>(&stB[soff]);
  float p0=pP.x,a0=pA.x,b0=pB.x, p1=pP.y,a1=pA.y,b1=pB.y;
  float p2=pP.z,a2=pA.z,b2=pB.z, p3=pP.w,a3=pA.w,b3=pB.w;
  #pragma unroll 4
  for (int j = 0; j < LCH; ++j) {
    uint2 kk = *reinterpret_cast<const uint2*>(&base[(size_t)j * 2048]);
    uint2 vv = *reinterpret_cast<const uint2*>(&base[(size_t)j * 2048 + 1024]);
    float k0 = bf2f(kk.x & 0xffff), k1 = bf2f(kk.x >> 16);
    float k2 = bf2f(kk.y & 0xffff), k3 = bf2f(kk.y >> 16);
    float v0 = bf2f(vv.x & 0xffff), v1 = bf2f(vv.x >> 16);
    float v2 = bf2f(vv.y & 0xffff), v3 = bf2f(vv.y >> 16);
    float ww0=u4.x+k0, ww1=u4.y+k1, ww2=u4.z+k2, ww3=u4.w+k3;
    float qq0=fmaxf(ww0,p0), qq1=fmaxf(ww1,p1), qq2=fmaxf(ww2,p2), qq3=fmaxf(ww3,p3);
    float e10=__expf(p0-qq0), e20=__expf(ww0-qq0);
    float e11=__expf(p1-qq1), e21=__expf(ww1-qq1);
    float e12=__expf(p2-qq2), e22=__expf(ww2-qq2);
    float e13=__expf(p3-qq3), e23=__expf(ww3-qq3);
    float o0=(e10*a0+e20*v0)*__builtin_amdgcn_rcpf(e10*b0+e20);
    float o1=(e11*a1+e21*v1)*__builtin_amdgcn_rcpf(e11*b1+e21);
    float o2=(e12*a2+e22*v2)*__builtin_amdgcn_rcpf(e12*b2+e22);
    float o3=(e13*a3+e23*v3)*__builtin_amdgcn_rcpf(e13*b3+e23);
    uint2 ow;
    ow.x = (unsigned)f2bf(o0) | ((unsigned)f2bf(o1) << 16);
    ow.y = (unsigned)f2bf(o2) | ((unsigned)f2bf(o3) << 16);
    *reinterpret_cast<uint2*>(&ob[(size_t)j * DIMSZ]) = ow;
    wkv_step(p0,a0,b0,k0,v0,w4.x);
    wkv_step(p1,a1,b1,k1,v1,w4.y);
    wkv_step(p2,a2,b2,k2,v2,w4.z);
    wkv_step(p3,a3,b3,k3,v3,w4.w);
  }
}

extern "C" void kernel_launch(void* const* d_in, const int* in_sizes, int n_in,
                              void* d_out, int out_size, void* d_ws, size_t ws_size,
                              hipStream_t stream) {
  const float* x  = (const float*)d_in[0];
  // d_in[1]=Wq, d_in[2]=bq: unused by the reference forward
  const float* Wk = (const float*)d_in[3];
  const float* bk = (const float*)d_in[4];
  const float* Wv = (const float*)d_in[5];
  const float* bv = (const float*)d_in[6];
  const float* wr = (const float*)d_in[7];
  const float* ur = (const float*)d_in[8];
  const float* Wo = (const float*)d_in[9];
  const float* bo = (const float*)d_in[10];
  float* out = (float*)d_out;

  char* ws = (char*)d_ws;
  unsigned short* xb   = (unsigned short*)(ws);               // 32MB  [16384][1024] bf16 (reused as O)
  unsigned short* WTkv = (unsigned short*)(ws + 33554432);    // 4MB   [2048][1024] bf16 (Wk^T ; Wv^T)
  unsigned short* WoT  = (unsigned short*)(ws + 37748736);    // 2MB   [1024][1024] bf16
  unsigned short* kvb  = (unsigned short*)(ws + 39845888);    // 64MB  [16384][2048] bf16

  // chunk-state scratch lives in d_out (64MB f32): fully overwritten by the
  // final GEMM afterwards, so this is free scratch during the wkv phase.
  float* stP = out;                       // 2MB (CCH*NCHAN floats)
  float* stA = out + CCH * NCHAN;         // 2MB
  float* stB = out + 2 * CCH * NCHAN;     // 2MB

  cast_x_kernel<<<dim3(16384), dim3(256), 0, stream>>>(x, xb);
  transpose_cast3_kernel<<<dim3(32, 32, 3), dim3(256), 0, stream>>>(
      Wk, Wv, Wo, WTkv, WTkv + 1024 * 1024, WoT);

  // k|v projection: [16384][1024] @ [1024][2048] -> bf16 kv buffer (+bk|bv)
  gemm256_kernel<1><<<dim3(64, 8), dim3(512), 131072, stream>>>(
      xb, WTkv, (void*)kvb, bk, bv, MTOT, 2048, 1024, 1024);

  // WKV chunked scan -> O (bf16) into xb (its x-bf16 contents are consumed)
  wkv_chunk_state_kernel<<<dim3(CCH * NB), dim3(256), 0, stream>>>(
      kvb, wr, stP, stA, stB);
  wkv_scan_kernel<<<dim3(NCHAN / 256), dim3(256), 0, stream>>>(wr, stP, stA, stB);
  wkv_out_kernel<<<dim3(CCH * NB), dim3(256), 0, stream>>>(
      kvb, wr, ur, stP, stA, stB, xb);

  // output projection: [16384][1024] @ [1024][1024] -> f32 d_out (+bo)
  gemm256_kernel<0><<<dim3(64, 4), dim3(512), 131072, stream>>>(
      xb, WoT, (void*)out, bo, bo, MTOT, 1024, 1024, 1024);
}